// Round 4
// baseline (1020.583 us; speedup 1.0000x reference)
//
#include <hip/hip_runtime.h>

// UAG-RNN 4-neighbor. Round-4: split each pass into
//   (A) streaming GEMM+transpose:  zT[b][o][pos][step] = W·in + (ba+bb)
//   (B) recurrence-only scan:      v_h = relu(z_h + Wb·v_{h-1})
// Round-3 counters showed the fused scan was bound by the per-step 64-line
// scatter gather (384 line-req/CU/step = 2460 cyc = measured 2480). Phase A
// streams x coalesced; phase B reads z contiguously per lane (4xdwordx4 per
// 16 steps). Buffers: z1T in d_out, hsT in d_ws, z2T overwrites d_out,
// scan-2 runs in-place on d_out (reads/writes provably disjoint per batch).

#define S   384
#define C64 64

typedef float v2f __attribute__((ext_vector_type(2)));
static __device__ __forceinline__ v2f mk2(float a, float b){ v2f r; r.x=a; r.y=b; return r; }

// ---------------- Phase A: GEMM + transpose ----------------
// in : [b][c][R][Sd]  (Sd contiguous),  out: [b][o][Sd][R]  (R contiguous)
// z = sum_c W[o][c]*in[b][c][R][Sd] + ba[o] + bb[o]
__global__ __launch_bounds__(256, 2)
void gemm_t_kernel(const float* __restrict__ in, float* __restrict__ outz,
                   const float* __restrict__ W, const float* __restrict__ ba,
                   const float* __restrict__ bb)
{
    __shared__ float xt[C64][256];     // [c][r*16+s]   64 KB
    __shared__ float Wl[C64 * C64];    // xor-swizzled  16 KB  (total 80 KB -> 2 WG/CU)

    const int t = threadIdx.x;
    const int o = t & 63, q = t >> 6;          // wave q, lane o
    int wg = blockIdx.x;
    const int b  = wg / 576;  wg -= b * 576;
    const int rt = wg / 24;   const int st = wg - rt * 24;
    const int r0 = rt * 16, s0 = st * 16;

    // stage W (swizzled: row o, col c at [o*64 + (c^(o&31))]) and the x tile
    const int sbase = b * C64 * S * S;
#pragma unroll
    for (int i = 0; i < 16; ++i) {
        int idx = i * 256 + t;                 // 0..4095
        int wo = idx >> 6, wc = idx & 63;
        Wl[wo * 64 + (wc ^ (wo & 31))] = W[idx];
        int sc = idx & 3, r = (idx >> 2) & 15, c = idx >> 6;
        float4 v = *(const float4*)(in + sbase + c * S * S + (r0 + r) * S + s0 + sc * 4);
        *(float4*)&xt[c][r * 16 + sc * 4] = v;
    }
    __syncthreads();

    const float cb = ba[o] + bb[o];
    v2f acc2[32];                              // acc[r][s']: 16 r x 4 s, s-pairs
#pragma unroll
    for (int j = 0; j < 32; ++j) acc2[j] = mk2(cb, cb);

    const int om = o & 31;
#pragma unroll 8
    for (int c = 0; c < 64; ++c) {
        float wcv = Wl[o * 64 + (c ^ om)];     // 2-way (free) bank pattern
        v2f w2 = mk2(wcv, wcv);
#pragma unroll
        for (int r = 0; r < 16; ++r) {
            float4 xv = *(const float4*)&xt[c][r * 16 + q * 4];  // wave-broadcast
            acc2[2*r+0] = __builtin_elementwise_fma(w2, mk2(xv.x, xv.y), acc2[2*r+0]);
            acc2[2*r+1] = __builtin_elementwise_fma(w2, mk2(xv.z, xv.w), acc2[2*r+1]);
        }
    }

    // store: for each of 4 s-columns, 16 contiguous r values = one full 64B line
#define AV(r, hi, lo) ((lo) ? acc2[2*(r)+(hi)].y : acc2[2*(r)+(hi)].x)
#pragma unroll
    for (int sp = 0; sp < 4; ++sp) {
        const int hi = sp >> 1, lo = sp & 1;
        float* po = outz + ((b * C64 + o) * S + (s0 + q * 4 + sp)) * S + r0;
        float4 A = { AV(0,hi,lo),  AV(1,hi,lo),  AV(2,hi,lo),  AV(3,hi,lo)  };
        float4 Bv= { AV(4,hi,lo),  AV(5,hi,lo),  AV(6,hi,lo),  AV(7,hi,lo)  };
        float4 Cv= { AV(8,hi,lo),  AV(9,hi,lo),  AV(10,hi,lo), AV(11,hi,lo) };
        float4 D = { AV(12,hi,lo), AV(13,hi,lo), AV(14,hi,lo), AV(15,hi,lo) };
        ((float4*)po)[0] = A; ((float4*)po)[1] = Bv;
        ((float4*)po)[2] = Cv; ((float4*)po)[3] = D;
    }
#undef AV
}

// ---------------- Phase B: recurrence-only scan ----------------
// z/out rows: base = ((b*64+o)*S + pos)*S + h.  v_h = relu(z_h + Wb·v_{h-1}).
// mode=0: v0 = init_in[b][o][0][pos] raw; mode=1: relu of same.
__global__ __launch_bounds__(64, 2)
void scan_kernel(const float* __restrict__ z, const float* __restrict__ init_in,
                 float* __restrict__ out, const float* __restrict__ Wb, int mode)
{
    __shared__ float vs[2][C64];
    const int o = threadIdx.x;
    const int g = blockIdx.x;
    const int b = g / S, pos = g - (g / S) * S;

    v2f wb2[32];
    {
        const float4* B4 = (const float4*)(Wb + o * C64);
#pragma unroll
        for (int i = 0; i < 16; ++i) {
            float4 qb = B4[i];
            wb2[2*i+0] = mk2(qb.x, qb.y);
            wb2[2*i+1] = mk2(qb.z, qb.w);
        }
#pragma unroll
        for (int i = 0; i < 32; ++i) asm volatile("" : "+v"(wb2[i]));  // no remat
    }

    const int rowb = ((b * C64 + o) * S + pos) * S;
    float v0 = init_in[((b * C64 + o) * S) * S + pos];
    if (mode) v0 = fmaxf(v0, 0.0f);
    vs[1][o] = v0;
    __builtin_amdgcn_wave_barrier();

    const float4* zrow = (const float4*)(z + rowb);
    float4 zb0 = zrow[0], zb1 = zrow[1], zb2 = zrow[2], zb3 = zrow[3];
    float4 zn0, zn1, zn2, zn3;
    float ob[16];
    ob[0] = v0;

#define STEP(PAR, IDX, ZV)                                                    \
    {                                                                         \
        const float4* vq4 = (const float4*)&vs[PAR][0];                       \
        v2f a0 = mk2(0.f,0.f), a1 = a0, a2 = a0, a3 = a0;                     \
        _Pragma("unroll")                                                     \
        for (int i = 0; i < 4; ++i) {                                         \
            float4 u0 = vq4[4*i+0], u1 = vq4[4*i+1];                          \
            float4 u2 = vq4[4*i+2], u3 = vq4[4*i+3];                          \
            a0 = __builtin_elementwise_fma(wb2[8*i+0], mk2(u0.x,u0.y), a0);   \
            a0 = __builtin_elementwise_fma(wb2[8*i+1], mk2(u0.z,u0.w), a0);   \
            a1 = __builtin_elementwise_fma(wb2[8*i+2], mk2(u1.x,u1.y), a1);   \
            a1 = __builtin_elementwise_fma(wb2[8*i+3], mk2(u1.z,u1.w), a1);   \
            a2 = __builtin_elementwise_fma(wb2[8*i+4], mk2(u2.x,u2.y), a2);   \
            a2 = __builtin_elementwise_fma(wb2[8*i+5], mk2(u2.z,u2.w), a2);   \
            a3 = __builtin_elementwise_fma(wb2[8*i+6], mk2(u3.x,u3.y), a3);   \
            a3 = __builtin_elementwise_fma(wb2[8*i+7], mk2(u3.z,u3.w), a3);   \
        }                                                                     \
        v2f sv = (a0 + a1) + (a2 + a3);                                       \
        float vnew = fmaxf(sv.x + sv.y + (ZV), 0.0f);                         \
        ob[IDX] = vnew;                                                       \
        vs[(PAR) ^ 1][o] = vnew;                                              \
        __builtin_amdgcn_wave_barrier();                                      \
    }

#define STORE16(BASE)                                                         \
    {                                                                         \
        float4* p = (float4*)(out + rowb + (BASE));                           \
        float4 q0 = {ob[0],  ob[1],  ob[2],  ob[3]};                          \
        float4 q1 = {ob[4],  ob[5],  ob[6],  ob[7]};                          \
        float4 q2 = {ob[8],  ob[9],  ob[10], ob[11]};                         \
        float4 q3 = {ob[12], ob[13], ob[14], ob[15]};                         \
        p[0] = q0; p[1] = q1; p[2] = q2; p[3] = q3;                           \
    }

    // batch 0: steps 1..15 (prefetch batch 1 first)
    zn0 = zrow[4]; zn1 = zrow[5]; zn2 = zrow[6]; zn3 = zrow[7];
    STEP(1, 1, zb0.y) STEP(0, 2, zb0.z) STEP(1, 3, zb0.w)
    STEP(0, 4, zb1.x) STEP(1, 5, zb1.y) STEP(0, 6, zb1.z) STEP(1, 7, zb1.w)
    STEP(0, 8, zb2.x) STEP(1, 9, zb2.y) STEP(0,10, zb2.z) STEP(1,11, zb2.w)
    STEP(0,12, zb3.x) STEP(1,13, zb3.y) STEP(0,14, zb3.z) STEP(1,15, zb3.w)
    STORE16(0)

    for (int k = 1; k < 24; ++k) {
        const int h0 = 16 * k;
        zb0 = zn0; zb1 = zn1; zb2 = zn2; zb3 = zn3;     // waits on prefetch
        if (k < 23) {                                   // prefetch batch k+1
            const int j4 = 4 * k + 4;
            zn0 = zrow[j4+0]; zn1 = zrow[j4+1]; zn2 = zrow[j4+2]; zn3 = zrow[j4+3];
        }
        STEP(0, 0, zb0.x) STEP(1, 1, zb0.y) STEP(0, 2, zb0.z) STEP(1, 3, zb0.w)
        STEP(0, 4, zb1.x) STEP(1, 5, zb1.y) STEP(0, 6, zb1.z) STEP(1, 7, zb1.w)
        STEP(0, 8, zb2.x) STEP(1, 9, zb2.y) STEP(0,10, zb2.z) STEP(1,11, zb2.w)
        STEP(0,12, zb3.x) STEP(1,13, zb3.y) STEP(0,14, zb3.z) STEP(1,15, zb3.w)
        STORE16(h0)
    }
#undef STEP
#undef STORE16
}

extern "C" void kernel_launch(void* const* d_in, const int* in_sizes, int n_in,
                              void* d_out, int out_size, void* d_ws, size_t ws_size,
                              hipStream_t stream) {
    const float* x  = (const float*)d_in[0];
    const float* W1 = (const float*)d_in[1];
    const float* b1 = (const float*)d_in[2];
    const float* W2 = (const float*)d_in[3];
    const float* b2 = (const float*)d_in[4];
    const float* W4 = (const float*)d_in[5];
    const float* b4 = (const float*)d_in[6];
    const float* W5 = (const float*)d_in[7];
    const float* b5 = (const float*)d_in[8];
    float* out = (float*)d_out;
    float* hsT = (float*)d_ws;     // 151 MB scratch: vertical-pass output (b,c,w,h)

    dim3 gb(2304), tb(256);        // 4 b x 24 x 24 tiles
    dim3 gs(4 * S), ts(C64);       // 1536 waves, one per (b,pos)

    // A1: z1T[b][o][w][h] = W1·x + b1 + b2            (z1T lives in d_out)
    gemm_t_kernel<<<gb, tb, 0, stream>>>(x, out, W1, b1, b2);
    // B1: vertical scan  -> hsT[b][o][w][h]           (init: raw x row 0)
    scan_kernel<<<gs, ts, 0, stream>>>(out, x, hsT, W2, 0);
    // A2: z2T[b][o][h][j] = W4·hs + b4 + b5           (overwrites d_out)
    gemm_t_kernel<<<gb, tb, 0, stream>>>(hsT, out, W4, b4, b5);
    // B2: horizontal scan, IN PLACE on d_out          (init: relu hsT col 0)
    scan_kernel<<<gs, ts, 0, stream>>>(out, hsT, out, W5, 1);
}